// Round 3
// baseline (1255.913 us; speedup 1.0000x reference)
//
#include <hip/hip_runtime.h>

typedef unsigned int uint;
typedef unsigned short ushort;

#define NN 1000000
#define KSZ 9
#define CH 16
#define KTOT 144          // KSZ*CH
#define NBLK 1024
#define TILES64 15625     // NN / 64
#define MAXT 16           // ceil(TILES64 / NBLK) tiles per block
#define WSHIFT 17         // window = idx >> 17: 8 windows x 131072 nodes x 32B = 4MB (one XCD L2)
#define NPASS 8

typedef float f32x4 __attribute__((ext_vector_type(4)));
typedef short s16x8 __attribute__((ext_vector_type(8)));

__device__ __forceinline__ float bf2f(ushort v) { return __uint_as_float(((uint)v) << 16); }
__device__ __forceinline__ ushort f2bf(float f) {
  uint u = __float_as_uint(f);
  return (ushort)((u + 0x7fffu + ((u >> 16) & 1u)) >> 16);   // RNE
}
__device__ __forceinline__ float leaky(float x) { return x >= 0.f ? x : 0.2f * x; }

// Deadlock-proof soft barrier: per-pass counter, device-scope atomics,
// bounded spin (timeout ~25us). Correctness never depends on it converging —
// it only enforces temporal clustering of the gather windows. R2's
// hipLaunchCooperativeKernel sat at exactly 4 blocks/CU with zero margin and
// failed silently (convs never ran); this cannot fail.
__device__ __forceinline__ void soft_barrier(int* bar, int wp) {
  __syncthreads();                       // whole block finished its pass
  if (threadIdx.x == 0) {
    __hip_atomic_fetch_add(&bar[wp], 1, __ATOMIC_RELAXED, __HIP_MEMORY_SCOPE_AGENT);
    int tries = 0;
    while (__hip_atomic_load(&bar[wp], __ATOMIC_RELAXED, __HIP_MEMORY_SCOPE_AGENT) < NBLK
           && ++tries < 96)
      __builtin_amdgcn_s_sleep(8);
  }
  __syncthreads();
}

// data fp32 -> bf16 copy (conv1 rounds to bf16 for MFMA anyway; bit-identical)
__global__ __launch_bounds__(256)
void k_cast(const float* __restrict__ in, ushort* __restrict__ out) {
  size_t i0 = ((size_t)blockIdx.x * 256 + (size_t)threadIdx.x) * 8;
  if (i0 >= (size_t)NN * CH) return;
  float4 a = *(const float4*)(in + i0);
  float4 b = *(const float4*)(in + i0 + 4);
  float e[8] = {a.x, a.y, a.z, a.w, b.x, b.y, b.z, b.w};
  uint pk[4];
#pragma unroll
  for (int p = 0; p < 4; ++p)
    pk[p] = (uint)f2bf(e[2*p]) | ((uint)f2bf(e[2*p+1]) << 16);
  *(uint4*)(out + i0) = *(uint4*)pk;
}

// ---------------------------------------------------------------------------
// Windowed gather-conv (non-cooperative). The random gather is line-fill
// bound: 9M random 128B line touches vs 4MB per-XCD L2 -> 41% refetch at the
// L2-miss fill ceiling. Partition the 32MB source into 8 x 4MB windows; all
// blocks gather only window-wp rows during pass wp (soft barrier between
// passes keeps the grid phase-aligned). During a pass the window is the only
// gathered working set -> L2-resident: misses drop to compulsory
// (8 XCD x 4MB x 8 windows = 256MB + ind). Fragments are zero except
// window rows; MFMA accumulates across passes (windows partition K exactly,
// fp32 acc order change only). acc: 16 tiles x f32x4 = 64 VGPR;
// __launch_bounds__(256,4) caps VGPR at 128 -> 4 blocks/CU, grid = capacity.
// ---------------------------------------------------------------------------
__global__ __launch_bounds__(256, 4)
void k_conv(const ushort* __restrict__ src, const int* __restrict__ ind,
            const float* __restrict__ w, const float* __restrict__ bias,
            ushort* __restrict__ outv, float* __restrict__ accumOut,
            int* __restrict__ bar) {
  const int lane = threadIdx.x & 63;
  const int wid  = threadIdx.x >> 6;
  const int o = lane & 15;     // node-within-tile for A rows; out channel for B/D
  const int q = lane >> 4;
  const int qh = q >> 1;
  const int ch0 = (q & 1) * 8; // 8-channel half of the 32B row this lane loads

  __shared__ int   idxs[4][MAXT][KTOT];   // 36,864B: all tiles' indices, staged once
  __shared__ float red[4][32];

  // B fragments: B[k][o] = w[c*144 + o*9 + j], k = j*16 + c; lane holds k = 32t + 8q + i
  s16x8 bfrag[5];
#pragma unroll
  for (int t = 0; t < 5; ++t) {
#pragma unroll
    for (int i = 0; i < 8; ++i) {
      int k = t * 32 + q * 8 + i;
      ushort wv = 0;
      if (k < KTOT) { int j = k >> 4, c = k & 15; wv = f2bf(w[(c * CH + o) * KSZ + j]); }
      bfrag[t][i] = (short)wv;
    }
  }

  float bo = bias ? bias[o] : 0.f;

  // stage ALL tiles' indices into wave-private LDS (ind read exactly once)
#pragma unroll
  for (int tt = 0; tt < MAXT; ++tt) {
    int g = blockIdx.x + tt * NBLK;
    if (g < TILES64) {
      int base9 = (g * 64 + wid * 16) * 9;
      idxs[wid][tt][lane]      = ind[base9 + lane];
      idxs[wid][tt][lane + 64] = ind[base9 + lane + 64];
      if (lane < KTOT - 128) idxs[wid][tt][lane + 128] = ind[base9 + lane + 128];
    }
  }

  f32x4 acc[MAXT];
#pragma unroll
  for (int tt = 0; tt < MAXT; ++tt) acc[tt] = (f32x4){0.f, 0.f, 0.f, 0.f};

  for (int wp = 0; wp < NPASS; ++wp) {
    soft_barrier(bar, wp);                 // phase-align all blocks on window wp
#pragma unroll
    for (int tt = 0; tt < MAXT; ++tt) {
      int g = blockIdx.x + tt * NBLK;
      if (g >= TILES64) continue;          // uniform branch
      const int* tix = idxs[wid][tt];
      // slot s covers k=32s..32s+31 -> neighbor j = 2s+qh (s<4), j=8 (s=4, q<2 only)
      int i0 = tix[o * KSZ + 0 + qh];
      int i1 = tix[o * KSZ + 2 + qh];
      int i2 = tix[o * KSZ + 4 + qh];
      int i3 = tix[o * KSZ + 6 + qh];
      int i4 = tix[o * KSZ + 8];
      const ushort* p0 = src + (size_t)i0 * CH + ch0;
      const ushort* p1 = src + (size_t)i1 * CH + ch0;
      const ushort* p2 = src + (size_t)i2 * CH + ch0;
      const ushort* p3 = src + (size_t)i3 * CH + ch0;
      const ushort* p4 = src + (size_t)i4 * CH + ch0;
      s16x8 z = {0,0,0,0,0,0,0,0};
      s16x8 a0 = z, a1 = z, a2 = z, a3 = z, a4 = z;
      // predicated loads: only window-wp rows; inactive lanes keep zeros ("+v" ties init)
      if ((i0 >> WSHIFT) == wp) asm volatile("global_load_dwordx4 %0, %1, off sc0" : "+v"(a0) : "v"(p0) : "memory");
      if ((i1 >> WSHIFT) == wp) asm volatile("global_load_dwordx4 %0, %1, off sc0" : "+v"(a1) : "v"(p1) : "memory");
      if ((i2 >> WSHIFT) == wp) asm volatile("global_load_dwordx4 %0, %1, off sc0" : "+v"(a2) : "v"(p2) : "memory");
      if ((i3 >> WSHIFT) == wp) asm volatile("global_load_dwordx4 %0, %1, off sc0" : "+v"(a3) : "v"(p3) : "memory");
      if (qh == 0 && (i4 >> WSHIFT) == wp)   // k-pad lanes (q>=2) stay zero
        asm volatile("global_load_dwordx4 %0, %1, off sc0" : "+v"(a4) : "v"(p4) : "memory");
      asm volatile("s_waitcnt vmcnt(0)" ::: "memory");
      __builtin_amdgcn_sched_barrier(0);     // rule 18: keep MFMAs below the wait
      acc[tt] = __builtin_amdgcn_mfma_f32_16x16x32_bf16(a0, bfrag[0], acc[tt], 0, 0, 0);
      acc[tt] = __builtin_amdgcn_mfma_f32_16x16x32_bf16(a1, bfrag[1], acc[tt], 0, 0, 0);
      acc[tt] = __builtin_amdgcn_mfma_f32_16x16x32_bf16(a2, bfrag[2], acc[tt], 0, 0, 0);
      acc[tt] = __builtin_amdgcn_mfma_f32_16x16x32_bf16(a3, bfrag[3], acc[tt], 0, 0, 0);
      acc[tt] = __builtin_amdgcn_mfma_f32_16x16x32_bf16(a4, bfrag[4], acc[tt], 0, 0, 0);
    }
  }

  // epilogue: bias, round, store, stats on the ROUNDED values
  float wsum = 0.f, wsq = 0.f;
#pragma unroll
  for (int tt = 0; tt < MAXT; ++tt) {
    int g = blockIdx.x + tt * NBLK;
    if (g >= TILES64) continue;
    int base = g * 64 + wid * 16;
#pragma unroll
    for (int r = 0; r < 4; ++r) {
      float v = acc[tt][r] + bo;
      ushort hv = f2bf(v);
      outv[(size_t)(base + q * 4 + r) * CH + o] = hv;
      float vr = bf2f(hv);
      wsum += vr;
      wsq  += vr * vr;
    }
  }

  // per-channel reduce: lanes o, o+16, o+32, o+48 -> block -> global atomic
  wsum += __shfl_xor(wsum, 16);  wsum += __shfl_xor(wsum, 32);
  wsq  += __shfl_xor(wsq, 16);   wsq  += __shfl_xor(wsq, 32);
  if (lane < 16) { red[wid][lane] = wsum; red[wid][16 + lane] = wsq; }
  __syncthreads();
  if (threadIdx.x < 32) {
    float s = red[0][threadIdx.x] + red[1][threadIdx.x] + red[2][threadIdx.x] + red[3][threadIdx.x];
    atomicAdd(&accumOut[threadIdx.x], s);   // [0..15]=sum, [16..31]=sumsq
  }
}

// in-place BN1 + leaky on out1 (bf16): h = f2bf(leaky(scale*x + shift))
__global__ __launch_bounds__(256)
void k_bn(ushort* __restrict__ io, const float* __restrict__ statsIn,
          const float* __restrict__ gamma, const float* __restrict__ beta) {
  __shared__ float dsc[16], dsh[16];
  if (threadIdx.x < 16) {
    int c = threadIdx.x;
    float s = statsIn[c], sq = statsIn[16 + c];
    float mean = s * (1.0f / NN);
    float var  = sq * (1.0f / NN) - mean * mean;
    float scale = gamma[c] * rsqrtf(var + 1e-5f);
    dsc[c] = scale; dsh[c] = beta[c] - mean * scale;
  }
  __syncthreads();
  size_t i0 = ((size_t)blockIdx.x * 256 + (size_t)threadIdx.x) * 8;
  if (i0 >= (size_t)NN * CH) return;
  int coff = (int)(i0 & 15);
  float sc[8], sh[8];
#pragma unroll
  for (int p = 0; p < 8; ++p) { sc[p] = dsc[coff + p]; sh[p] = dsh[coff + p]; }
  uint4 a = *(const uint4*)(io + i0);
  uint ua[4] = {a.x, a.y, a.z, a.w};
  uint pk[4];
#pragma unroll
  for (int p = 0; p < 4; ++p) {
    float x0 = __uint_as_float(ua[p] << 16);
    float x1 = __uint_as_float(ua[p] & 0xffff0000u);
    float y0 = leaky(sc[2*p]   * x0 + sh[2*p]);
    float y1 = leaky(sc[2*p+1] * x1 + sh[2*p+1]);
    pk[p] = (uint)f2bf(y0) | ((uint)f2bf(y1) << 16);
  }
  *(uint4*)(io + i0) = *(uint4*)pk;
}

// out = leaky(scale2*out2 + shift2 + data), fp32; BN2 derived per block
__global__ __launch_bounds__(256)
void k_final(const ushort* __restrict__ o2, const float* __restrict__ data,
             const float* __restrict__ statsIn, const float* __restrict__ gamma,
             const float* __restrict__ beta, float* __restrict__ out) {
  __shared__ float dsc[16], dsh[16];
  if (threadIdx.x < 16) {
    int c = threadIdx.x;
    float s = statsIn[c], sq = statsIn[16 + c];
    float mean = s * (1.0f / NN);
    float var  = sq * (1.0f / NN) - mean * mean;
    float scale = gamma[c] * rsqrtf(var + 1e-5f);
    dsc[c] = scale; dsh[c] = beta[c] - mean * scale;
  }
  __syncthreads();
  size_t t = (size_t)blockIdx.x * 256 + threadIdx.x;
  size_t i0 = t * 8;
  if (i0 >= (size_t)NN * CH) return;
  int coff = (int)(i0 & 15);
  float sc[8], sh[8];
#pragma unroll
  for (int p = 0; p < 8; ++p) { sc[p] = dsc[coff + p]; sh[p] = dsh[coff + p]; }
  uint4 a = *(const uint4*)(o2 + i0);
  float4 d0 = *(const float4*)(data + i0);
  float4 d1 = *(const float4*)(data + i0 + 4);
  uint ua[4] = {a.x, a.y, a.z, a.w};
  float dd[8] = {d0.x, d0.y, d0.z, d0.w, d1.x, d1.y, d1.z, d1.w};
  float y[8];
#pragma unroll
  for (int p = 0; p < 4; ++p) {
    float x0 = __uint_as_float(ua[p] << 16);
    float x1 = __uint_as_float(ua[p] & 0xffff0000u);
    y[2*p]   = leaky(sc[2*p]   * x0 + sh[2*p]   + dd[2*p]);
    y[2*p+1] = leaky(sc[2*p+1] * x1 + sh[2*p+1] + dd[2*p+1]);
  }
  float4 r0 = {y[0], y[1], y[2], y[3]};
  float4 r1 = {y[4], y[5], y[6], y[7]};
  *(float4*)(out + i0) = r0;
  *(float4*)(out + i0 + 4) = r1;
}

extern "C" void kernel_launch(void* const* d_in, const int* in_sizes, int n_in,
                              void* d_out, int out_size, void* d_ws, size_t ws_size,
                              hipStream_t stream) {
  const float* data   = (const float*)d_in[0];
  const int*   ind    = (const int*)d_in[1];
  const float* w1     = (const float*)d_in[2];
  const float* b1     = (const float*)d_in[3];
  const float* gamma1 = (const float*)d_in[4];
  const float* beta1  = (const float*)d_in[5];
  const float* w2     = (const float*)d_in[6];
  const float* gamma2 = (const float*)d_in[7];
  const float* beta2  = (const float*)d_in[8];
  float* out = (float*)d_out;

  // d_out (64MB fp32) doubles as scratch until k_final overwrites:
  //   [0,32MB)  = out1 bf16 (conv1 raw, then BN1+leaky in place)
  //   [32,64MB) = dataB bf16 (pre-rounded data; dead after conv1)
  ushort* out1  = (ushort*)d_out;
  ushort* dataB = out1 + (size_t)NN * CH;
  // ws: accum1[32] | accum2[32] | bar1[8] | bar2[8] | pad | out2 bf16 (32MB @ +4096)
  float*  accum1 = (float*)d_ws;
  float*  accum2 = accum1 + 32;
  int*    bar1   = (int*)((char*)d_ws + 256);
  int*    bar2   = bar1 + 8;
  ushort* out2   = (ushort*)((char*)d_ws + 4096);

  hipMemsetAsync(d_ws, 0, 512, stream);   // zero accumulators + barrier counters

  hipLaunchKernelGGL(k_cast, dim3((NN * CH / 8 + 255) / 256), dim3(256), 0, stream,
                     data, dataB);

  // conv1: dataB -> out1 raw + stats (windowed, soft-barrier phase alignment)
  hipLaunchKernelGGL(k_conv, dim3(NBLK), dim3(256), 0, stream,
                     dataB, ind, w1, b1, out1, accum1, bar1);

  // BN1 + leaky in place on out1
  hipLaunchKernelGGL(k_bn, dim3((NN * CH / 8 + 255) / 256), dim3(256), 0, stream,
                     out1, accum1, gamma1, beta1);

  // conv2: out1 (=h1) -> out2 raw + stats
  hipLaunchKernelGGL(k_conv, dim3(NBLK), dim3(256), 0, stream,
                     out1, ind, w2, (const float*)nullptr, out2, accum2, bar2);

  // residual + BN2 + leaky -> d_out (scratch regions dead)
  hipLaunchKernelGGL(k_final, dim3((NN * CH / 8 + 255) / 256), dim3(256), 0, stream,
                     out2, data, accum2, gamma2, beta2, out);
}

// Round 4
// 490.287 us; speedup vs baseline: 2.5616x; 2.5616x over previous
//
#include <hip/hip_runtime.h>

typedef unsigned int uint;
typedef unsigned short ushort;

#define NN 1000000
#define KSZ 9
#define CH 16
#define KTOT 144          // KSZ*CH
#define NBLK 1024
#define TILES64 15625     // NN / 64
#define MAXT 16           // ceil(TILES64 / NBLK) tiles per block

typedef float f32x4 __attribute__((ext_vector_type(4)));
typedef short s16x8 __attribute__((ext_vector_type(8)));

__device__ __forceinline__ float bf2f(ushort v) { return __uint_as_float(((uint)v) << 16); }
__device__ __forceinline__ ushort f2bf(float f) {
  uint u = __float_as_uint(f);
  return (ushort)((u + 0x7fffu + ((u >> 16) & 1u)) >> 16);   // RNE
}
__device__ __forceinline__ float leaky(float x) { return x >= 0.f ? x : 0.2f * x; }

// data fp32 -> bf16 copy (conv1 rounds to bf16 for MFMA anyway; bit-identical)
__global__ __launch_bounds__(256)
void k_cast(const float* __restrict__ in, ushort* __restrict__ out) {
  size_t i0 = ((size_t)blockIdx.x * 256 + (size_t)threadIdx.x) * 8;
  if (i0 >= (size_t)NN * CH) return;
  float4 a = *(const float4*)(in + i0);
  float4 b = *(const float4*)(in + i0 + 4);
  float e[8] = {a.x, a.y, a.z, a.w, b.x, b.y, b.z, b.w};
  uint pk[4];
#pragma unroll
  for (int p = 0; p < 4; ++p)
    pk[p] = (uint)f2bf(e[2*p]) | ((uint)f2bf(e[2*p+1]) << 16);
  *(uint4*)(out + i0) = *(uint4*)pk;
}

// ---------------------------------------------------------------------------
// Depth-2 pipelined gather-conv. R3's A/B proved the gather is NOT at a fill
// ceiling: it is latency x concurrency bound (Little's law: R1 held only 5
// loads in flight then vmcnt(0) -> 27 outstanding lines/CU -> the measured
// 0.082 fills/cy/CU). Fix: single sweep (no windows/barriers), all 16 tiles'
// indices staged in LDS up front, and per stage issue tile t+1's 5 gather
// loads BEFORE waiting on tile t with a counted s_waitcnt vmcnt(5) — 10 loads
// in flight per wave, idx ds_read latency hidden under the previous tile's
// loads. acc is per-tile (no cross-pass accumulation): ~100 VGPR, 4 blocks/CU
// (LDS 37.4KB), grid = exact co-residency capacity.
// ---------------------------------------------------------------------------
__global__ __launch_bounds__(256, 4)
void k_conv(const ushort* __restrict__ src, const int* __restrict__ ind,
            const float* __restrict__ w, const float* __restrict__ bias,
            ushort* __restrict__ outv, float* __restrict__ accumOut) {
  const int lane = threadIdx.x & 63;
  const int wid  = threadIdx.x >> 6;
  const int o = lane & 15;     // node-within-tile for A rows; out channel for B/D
  const int q = lane >> 4;
  const int qh = q >> 1;
  const int ch0 = (q & 1) * 8; // 8-channel half of the 32B row this lane loads
  const int o9 = o * KSZ;

  __shared__ int   idxs[4][MAXT][KTOT];   // 36,864B: all tiles' indices, staged once
  __shared__ float red[4][32];

  // B fragments: B[k][o] = w[c*144 + o*9 + j], k = j*16 + c; lane holds k = 32t + 8q + i
  // k >= 144 (the K-pad) is zero in B, so A-pad content is DON'T-CARE (finite).
  s16x8 bfrag[5];
#pragma unroll
  for (int t = 0; t < 5; ++t) {
#pragma unroll
    for (int i = 0; i < 8; ++i) {
      int k = t * 32 + q * 8 + i;
      ushort wv = 0;
      if (k < KTOT) { int j = k >> 4, c = k & 15; wv = f2bf(w[(c * CH + o) * KSZ + j]); }
      bfrag[t][i] = (short)wv;
    }
  }

  const float bo = bias ? bias[o] : 0.f;
  const int NT = (TILES64 - 1 - blockIdx.x) / NBLK + 1;   // 15 or 16 tiles

  // stage ALL tiles' indices into wave-private LDS (ind read exactly once)
#pragma unroll
  for (int tt = 0; tt < MAXT; ++tt) {
    if (tt < NT) {
      int base9 = ((blockIdx.x + tt * NBLK) * 64 + wid * 16) * 9;
      idxs[wid][tt][lane]      = ind[base9 + lane];
      idxs[wid][tt][lane + 64] = ind[base9 + lane + 64];
      if (lane < KTOT - 128) idxs[wid][tt][lane + 128] = ind[base9 + lane + 128];
    }
  }
  // clean vmcnt slate before counted waits (staging loads/ds_writes fully drained)
  asm volatile("s_waitcnt vmcnt(0) lgkmcnt(0)" ::: "memory");
  __builtin_amdgcn_sched_barrier(0);

  float wsum = 0.f, wsq = 0.f;
  s16x8 A0, A1, A2, A3, A4, B0, B1, B2, B3, B4;

  // issue tile tt's 5 gather loads (j = {0,2,4,6}+qh and j=8; 16B/lane, the
  // q-pair's two halves coalesce into one 32B request)
#define ISSUE(tt, L0, L1, L2, L3, L4)                                          \
  do {                                                                         \
    if ((tt) < NT) {                                                           \
      const int* tix = &idxs[wid][(tt)][0];                                    \
      int j0 = tix[o9 + 0 + qh];                                               \
      int j1 = tix[o9 + 2 + qh];                                               \
      int j2 = tix[o9 + 4 + qh];                                               \
      int j3 = tix[o9 + 6 + qh];                                               \
      int j4 = tix[o9 + 8];                                                    \
      const ushort* p0 = src + (size_t)j0 * CH + ch0;                          \
      const ushort* p1 = src + (size_t)j1 * CH + ch0;                          \
      const ushort* p2 = src + (size_t)j2 * CH + ch0;                          \
      const ushort* p3 = src + (size_t)j3 * CH + ch0;                          \
      const ushort* p4 = src + (size_t)j4 * CH + ch0;                          \
      asm volatile("global_load_dwordx4 %0, %1, off sc0" : "=v"(L0) : "v"(p0) : "memory"); \
      asm volatile("global_load_dwordx4 %0, %1, off sc0" : "=v"(L1) : "v"(p1) : "memory"); \
      asm volatile("global_load_dwordx4 %0, %1, off sc0" : "=v"(L2) : "v"(p2) : "memory"); \
      asm volatile("global_load_dwordx4 %0, %1, off sc0" : "=v"(L3) : "v"(p3) : "memory"); \
      asm volatile("global_load_dwordx4 %0, %1, off sc0" : "=v"(L4) : "v"(p4) : "memory"); \
    }                                                                          \
  } while (0)

#define COMPUTE(tt, L0, L1, L2, L3, L4)                                        \
  do {                                                                         \
    if ((tt) < NT) {                                                           \
      f32x4 acc = {0.f, 0.f, 0.f, 0.f};                                        \
      acc = __builtin_amdgcn_mfma_f32_16x16x32_bf16(L0, bfrag[0], acc, 0, 0, 0); \
      acc = __builtin_amdgcn_mfma_f32_16x16x32_bf16(L1, bfrag[1], acc, 0, 0, 0); \
      acc = __builtin_amdgcn_mfma_f32_16x16x32_bf16(L2, bfrag[2], acc, 0, 0, 0); \
      acc = __builtin_amdgcn_mfma_f32_16x16x32_bf16(L3, bfrag[3], acc, 0, 0, 0); \
      acc = __builtin_amdgcn_mfma_f32_16x16x32_bf16(L4, bfrag[4], acc, 0, 0, 0); \
      int base = (blockIdx.x + (tt) * NBLK) * 64 + wid * 16;                   \
      _Pragma("unroll")                                                        \
      for (int r = 0; r < 4; ++r) {                                            \
        float v = acc[r] + bo;                                                 \
        ushort hv = f2bf(v);                                                   \
        outv[(size_t)(base + q * 4 + r) * CH + o] = hv;                        \
        float vr = bf2f(hv);                                                   \
        wsum += vr;                                                            \
        wsq  += vr * vr;                                                       \
      }                                                                        \
    }                                                                          \
  } while (0)

  // stage t: issue t+1 (if any), counted-wait for t's loads, compute t.
  // vmcnt(5): outstanding at the wait = loads(t){5} + stores(t-1){4} +
  // loads(t+1){5}; waiting to <=5 drains loads(t)+stores, keeps t+1 in flight.
#define STAGE(t, C0, C1, C2, C3, C4, N0, N1, N2, N3, N4)                       \
  do {                                                                         \
    if ((t) + 1 < NT) {                                                        \
      ISSUE((t) + 1, N0, N1, N2, N3, N4);                                      \
      asm volatile("s_waitcnt vmcnt(5)" ::: "memory");                         \
    } else {                                                                   \
      asm volatile("s_waitcnt vmcnt(0)" ::: "memory");                         \
    }                                                                          \
    __builtin_amdgcn_sched_barrier(0);  /* rule 18: keep MFMAs below wait */   \
    COMPUTE(t, C0, C1, C2, C3, C4);                                            \
  } while (0)

  ISSUE(0, A0, A1, A2, A3, A4);
  STAGE(0,  A0, A1, A2, A3, A4,  B0, B1, B2, B3, B4);
  STAGE(1,  B0, B1, B2, B3, B4,  A0, A1, A2, A3, A4);
  STAGE(2,  A0, A1, A2, A3, A4,  B0, B1, B2, B3, B4);
  STAGE(3,  B0, B1, B2, B3, B4,  A0, A1, A2, A3, A4);
  STAGE(4,  A0, A1, A2, A3, A4,  B0, B1, B2, B3, B4);
  STAGE(5,  B0, B1, B2, B3, B4,  A0, A1, A2, A3, A4);
  STAGE(6,  A0, A1, A2, A3, A4,  B0, B1, B2, B3, B4);
  STAGE(7,  B0, B1, B2, B3, B4,  A0, A1, A2, A3, A4);
  STAGE(8,  A0, A1, A2, A3, A4,  B0, B1, B2, B3, B4);
  STAGE(9,  B0, B1, B2, B3, B4,  A0, A1, A2, A3, A4);
  STAGE(10, A0, A1, A2, A3, A4,  B0, B1, B2, B3, B4);
  STAGE(11, B0, B1, B2, B3, B4,  A0, A1, A2, A3, A4);
  STAGE(12, A0, A1, A2, A3, A4,  B0, B1, B2, B3, B4);
  STAGE(13, B0, B1, B2, B3, B4,  A0, A1, A2, A3, A4);
  STAGE(14, A0, A1, A2, A3, A4,  B0, B1, B2, B3, B4);
  STAGE(15, B0, B1, B2, B3, B4,  A0, A1, A2, A3, A4);
#undef STAGE
#undef COMPUTE
#undef ISSUE

  // per-channel reduce: lanes o, o+16, o+32, o+48 -> block -> global atomic
  wsum += __shfl_xor(wsum, 16);  wsum += __shfl_xor(wsum, 32);
  wsq  += __shfl_xor(wsq, 16);   wsq  += __shfl_xor(wsq, 32);
  if (lane < 16) { red[wid][lane] = wsum; red[wid][16 + lane] = wsq; }
  __syncthreads();
  if (threadIdx.x < 32) {
    float s = red[0][threadIdx.x] + red[1][threadIdx.x] + red[2][threadIdx.x] + red[3][threadIdx.x];
    atomicAdd(&accumOut[threadIdx.x], s);   // [0..15]=sum, [16..31]=sumsq
  }
}

// in-place BN1 + leaky on out1 (bf16): h = f2bf(leaky(scale*x + shift))
__global__ __launch_bounds__(256)
void k_bn(ushort* __restrict__ io, const float* __restrict__ statsIn,
          const float* __restrict__ gamma, const float* __restrict__ beta) {
  __shared__ float dsc[16], dsh[16];
  if (threadIdx.x < 16) {
    int c = threadIdx.x;
    float s = statsIn[c], sq = statsIn[16 + c];
    float mean = s * (1.0f / NN);
    float var  = sq * (1.0f / NN) - mean * mean;
    float scale = gamma[c] * rsqrtf(var + 1e-5f);
    dsc[c] = scale; dsh[c] = beta[c] - mean * scale;
  }
  __syncthreads();
  size_t i0 = ((size_t)blockIdx.x * 256 + (size_t)threadIdx.x) * 8;
  if (i0 >= (size_t)NN * CH) return;
  int coff = (int)(i0 & 15);
  float sc[8], sh[8];
#pragma unroll
  for (int p = 0; p < 8; ++p) { sc[p] = dsc[coff + p]; sh[p] = dsh[coff + p]; }
  uint4 a = *(const uint4*)(io + i0);
  uint ua[4] = {a.x, a.y, a.z, a.w};
  uint pk[4];
#pragma unroll
  for (int p = 0; p < 4; ++p) {
    float x0 = __uint_as_float(ua[p] << 16);
    float x1 = __uint_as_float(ua[p] & 0xffff0000u);
    float y0 = leaky(sc[2*p]   * x0 + sh[2*p]);
    float y1 = leaky(sc[2*p+1] * x1 + sh[2*p+1]);
    pk[p] = (uint)f2bf(y0) | ((uint)f2bf(y1) << 16);
  }
  *(uint4*)(io + i0) = *(uint4*)pk;
}

// out = leaky(scale2*out2 + shift2 + data), fp32; BN2 derived per block
__global__ __launch_bounds__(256)
void k_final(const ushort* __restrict__ o2, const float* __restrict__ data,
             const float* __restrict__ statsIn, const float* __restrict__ gamma,
             const float* __restrict__ beta, float* __restrict__ out) {
  __shared__ float dsc[16], dsh[16];
  if (threadIdx.x < 16) {
    int c = threadIdx.x;
    float s = statsIn[c], sq = statsIn[16 + c];
    float mean = s * (1.0f / NN);
    float var  = sq * (1.0f / NN) - mean * mean;
    float scale = gamma[c] * rsqrtf(var + 1e-5f);
    dsc[c] = scale; dsh[c] = beta[c] - mean * scale;
  }
  __syncthreads();
  size_t t = (size_t)blockIdx.x * 256 + threadIdx.x;
  size_t i0 = t * 8;
  if (i0 >= (size_t)NN * CH) return;
  int coff = (int)(i0 & 15);
  float sc[8], sh[8];
#pragma unroll
  for (int p = 0; p < 8; ++p) { sc[p] = dsc[coff + p]; sh[p] = dsh[coff + p]; }
  uint4 a = *(const uint4*)(o2 + i0);
  float4 d0 = *(const float4*)(data + i0);
  float4 d1 = *(const float4*)(data + i0 + 4);
  uint ua[4] = {a.x, a.y, a.z, a.w};
  float dd[8] = {d0.x, d0.y, d0.z, d0.w, d1.x, d1.y, d1.z, d1.w};
  float y[8];
#pragma unroll
  for (int p = 0; p < 4; ++p) {
    float x0 = __uint_as_float(ua[p] << 16);
    float x1 = __uint_as_float(ua[p] & 0xffff0000u);
    y[2*p]   = leaky(sc[2*p]   * x0 + sh[2*p]   + dd[2*p]);
    y[2*p+1] = leaky(sc[2*p+1] * x1 + sh[2*p+1] + dd[2*p+1]);
  }
  float4 r0 = {y[0], y[1], y[2], y[3]};
  float4 r1 = {y[4], y[5], y[6], y[7]};
  *(float4*)(out + i0) = r0;
  *(float4*)(out + i0 + 4) = r1;
}

extern "C" void kernel_launch(void* const* d_in, const int* in_sizes, int n_in,
                              void* d_out, int out_size, void* d_ws, size_t ws_size,
                              hipStream_t stream) {
  const float* data   = (const float*)d_in[0];
  const int*   ind    = (const int*)d_in[1];
  const float* w1     = (const float*)d_in[2];
  const float* b1     = (const float*)d_in[3];
  const float* gamma1 = (const float*)d_in[4];
  const float* beta1  = (const float*)d_in[5];
  const float* w2     = (const float*)d_in[6];
  const float* gamma2 = (const float*)d_in[7];
  const float* beta2  = (const float*)d_in[8];
  float* out = (float*)d_out;

  // d_out (64MB fp32) doubles as scratch until k_final overwrites:
  //   [0,32MB)  = out1 bf16 (conv1 raw, then BN1+leaky in place)
  //   [32,64MB) = dataB bf16 (pre-rounded data; dead after conv1)
  ushort* out1  = (ushort*)d_out;
  ushort* dataB = out1 + (size_t)NN * CH;
  // ws: accum1[32] | accum2[32] | pad | out2 bf16 (32MB @ +4096)
  float*  accum1 = (float*)d_ws;
  float*  accum2 = accum1 + 32;
  ushort* out2   = (ushort*)((char*)d_ws + 4096);

  hipMemsetAsync(d_ws, 0, 256, stream);   // zero both stat accumulators

  hipLaunchKernelGGL(k_cast, dim3((NN * CH / 8 + 255) / 256), dim3(256), 0, stream,
                     data, dataB);

  // conv1: dataB -> out1 raw + stats
  hipLaunchKernelGGL(k_conv, dim3(NBLK), dim3(256), 0, stream,
                     dataB, ind, w1, b1, out1, accum1);

  // BN1 + leaky in place on out1
  hipLaunchKernelGGL(k_bn, dim3((NN * CH / 8 + 255) / 256), dim3(256), 0, stream,
                     out1, accum1, gamma1, beta1);

  // conv2: out1 (=h1) -> out2 raw + stats
  hipLaunchKernelGGL(k_conv, dim3(NBLK), dim3(256), 0, stream,
                     out1, ind, w2, (const float*)nullptr, out2, accum2);

  // residual + BN2 + leaky -> d_out (scratch regions dead)
  hipLaunchKernelGGL(k_final, dim3((NN * CH / 8 + 255) / 256), dim3(256), 0, stream,
                     out2, data, accum2, gamma2, beta2, out);
}

// Round 5
// 471.233 us; speedup vs baseline: 2.6652x; 1.0404x over previous
//
#include <hip/hip_runtime.h>

typedef unsigned int uint;
typedef unsigned short ushort;

#define NN 1000000
#define KSZ 9
#define CH 16
#define KTOT 144          // KSZ*CH
#define NBLK 2048
#define TILES64 15625     // NN / 64

typedef float f32x4 __attribute__((ext_vector_type(4)));
typedef short s16x8 __attribute__((ext_vector_type(8)));

__device__ __forceinline__ float bf2f(ushort v) { return __uint_as_float(((uint)v) << 16); }
__device__ __forceinline__ ushort f2bf(float f) {
  uint u = __float_as_uint(f);
  return (ushort)((u + 0x7fffu + ((u >> 16) & 1u)) >> 16);   // RNE
}
__device__ __forceinline__ float leaky(float x) { return x >= 0.f ? x : 0.2f * x; }

// ---------------------------------------------------------------------------
// Direct-to-fragment gather conv (R1-proven body, 158.5us/conv @1024 blocks).
// One wave owns a 16-node tile. A-fragment for lane (o=lane&15, q=lane>>4) at
// K-slot s is row ind[(base+o)*9 + j], j = 2s+(q>>1) (slot 4: j=8, q<2),
// channels (q&1)*8..+7.
//   FP32SRC: src = fp32 data; 2x16B loads/slot, v_cvt_pk_bf16_f32 to bf16
//            fragment (removes the k_cast pre-pass + its launch gap).
//   else   : src = out1 raw bf16; 1x16B load/slot; BN1+leaky applied
//            in-register, scale/shift derived in-prologue from the atomic
//            stats accumulator (removes the k_bn pass + its launch gap).
// Gather is at a concurrency-insensitive ~3.3TB/s line-fill ceiling
// (R3: predication collapsed rate; R4: 2x in-flight changed nothing), so the
// simple per-tile load->vmcnt(0)->MFMA body is as fast as deep pipelining.
// NBLK=2048 (8 blocks/CU) is this round's occupancy diagnostic.
// ---------------------------------------------------------------------------
template<bool FP32SRC>
__global__ __launch_bounds__(256)
void k_conv(const void* __restrict__ srcv, const int* __restrict__ ind,
            const float* __restrict__ w, const float* __restrict__ bias,
            const float* __restrict__ statsIn, const float* __restrict__ gamma,
            const float* __restrict__ beta,
            ushort* __restrict__ outv, float* __restrict__ accumOut) {
  const int lane = threadIdx.x & 63;
  const int wid  = threadIdx.x >> 6;
  const int o = lane & 15;     // node-within-tile for A rows; out channel for B/D
  const int q = lane >> 4;
  const int qh = q >> 1;
  const int ch0 = (q & 1) * 8; // 8-channel half of the row this lane loads
  const int o9 = o * KSZ;

  __shared__ int   idxs[4][160];
  __shared__ float red[4][32];
  __shared__ float dsc[16], dsh[16];

  // B fragments: B[k][o] = w[c*144 + o*9 + j], k = j*16 + c; lane holds k = 32t + 8q + i
  // k >= 144 (K-pad) is zero in B, so pad A content is don't-care (finite).
  s16x8 bfrag[5];
#pragma unroll
  for (int t = 0; t < 5; ++t) {
#pragma unroll
    for (int i = 0; i < 8; ++i) {
      int k = t * 32 + q * 8 + i;
      ushort wv = 0;
      if (k < KTOT) { int j = k >> 4, c = k & 15; wv = f2bf(w[(c * CH + o) * KSZ + j]); }
      bfrag[t][i] = (short)wv;
    }
  }

  float bo = 0.f;
  float sc8[8], sh8[8];
  if constexpr (FP32SRC) {
    bo = bias[o];
  } else {
    // derive BN1 scale/shift per block from the atomic accumulator
    if (threadIdx.x < 16) {
      int c = threadIdx.x;
      float s = statsIn[c], sq = statsIn[16 + c];
      float mean = s * (1.0f / NN);
      float var  = sq * (1.0f / NN) - mean * mean;
      float scale = gamma[c] * rsqrtf(var + 1e-5f);
      dsc[c] = scale; dsh[c] = beta[c] - mean * scale;
    }
    __syncthreads();
#pragma unroll
    for (int i = 0; i < 8; ++i) { sc8[i] = dsc[ch0 + i]; sh8[i] = dsh[ch0 + i]; }
  }

  int* idxw = idxs[wid];
  float wsum = 0.f, wsq = 0.f;

  for (int g = blockIdx.x; g < TILES64; g += NBLK) {
    const int base  = g * 64 + wid * 16;
    const int base9 = base * 9;

    // stage this wave's 144 indices (coalesced; wave-private -> no barrier)
    idxw[lane]      = ind[base9 + lane];
    idxw[lane + 64] = ind[base9 + lane + 64];
    if (lane < KTOT - 128) idxw[lane + 128] = ind[base9 + lane + 128];

    int i0 = idxw[o9 + 0 + qh];
    int i1 = idxw[o9 + 2 + qh];
    int i2 = idxw[o9 + 4 + qh];
    int i3 = idxw[o9 + 6 + qh];
    int i4 = idxw[o9 + 8];

    s16x8 a0, a1, a2, a3, a4;
    if constexpr (FP32SRC) {
      const float* fsrc = (const float*)srcv;
      const float* p0 = fsrc + (size_t)i0 * CH + ch0;
      const float* p1 = fsrc + (size_t)i1 * CH + ch0;
      const float* p2 = fsrc + (size_t)i2 * CH + ch0;
      const float* p3 = fsrc + (size_t)i3 * CH + ch0;
      const float* p4 = fsrc + (size_t)i4 * CH + ch0;
      f32x4 l0a, l0b, l1a, l1b, l2a, l2b, l3a, l3b, l4a, l4b;
      asm volatile("global_load_dwordx4 %0, %1, off sc0"           : "=&v"(l0a) : "v"(p0) : "memory");
      asm volatile("global_load_dwordx4 %0, %1, off offset:16 sc0" : "=&v"(l0b) : "v"(p0) : "memory");
      asm volatile("global_load_dwordx4 %0, %1, off sc0"           : "=&v"(l1a) : "v"(p1) : "memory");
      asm volatile("global_load_dwordx4 %0, %1, off offset:16 sc0" : "=&v"(l1b) : "v"(p1) : "memory");
      asm volatile("global_load_dwordx4 %0, %1, off sc0"           : "=&v"(l2a) : "v"(p2) : "memory");
      asm volatile("global_load_dwordx4 %0, %1, off offset:16 sc0" : "=&v"(l2b) : "v"(p2) : "memory");
      asm volatile("global_load_dwordx4 %0, %1, off sc0"           : "=&v"(l3a) : "v"(p3) : "memory");
      asm volatile("global_load_dwordx4 %0, %1, off offset:16 sc0" : "=&v"(l3b) : "v"(p3) : "memory");
      asm volatile("global_load_dwordx4 %0, %1, off sc0"           : "=&v"(l4a) : "v"(p4) : "memory");
      asm volatile("global_load_dwordx4 %0, %1, off offset:16 sc0" : "=&v"(l4b) : "v"(p4) : "memory");
      asm volatile("s_waitcnt vmcnt(0)" ::: "memory");
      __builtin_amdgcn_sched_barrier(0);   // rule 18: keep consumers below the wait
      // fp32 -> packed bf16 fragment (RNE; matches reference bf16 rounding class)
      auto pack = [](f32x4 lo, f32x4 hi) -> s16x8 {
        uint u0, u1, u2, u3;
        asm("v_cvt_pk_bf16_f32 %0, %1, %2" : "=v"(u0) : "v"(lo[0]), "v"(lo[1]));
        asm("v_cvt_pk_bf16_f32 %0, %1, %2" : "=v"(u1) : "v"(lo[2]), "v"(lo[3]));
        asm("v_cvt_pk_bf16_f32 %0, %1, %2" : "=v"(u2) : "v"(hi[0]), "v"(hi[1]));
        asm("v_cvt_pk_bf16_f32 %0, %1, %2" : "=v"(u3) : "v"(hi[2]), "v"(hi[3]));
        uint4 uu = {u0, u1, u2, u3};
        return *(s16x8*)&uu;
      };
      a0 = pack(l0a, l0b); a1 = pack(l1a, l1b); a2 = pack(l2a, l2b);
      a3 = pack(l3a, l3b); a4 = pack(l4a, l4b);
    } else {
      const ushort* bsrc = (const ushort*)srcv;
      const ushort* p0 = bsrc + (size_t)i0 * CH + ch0;
      const ushort* p1 = bsrc + (size_t)i1 * CH + ch0;
      const ushort* p2 = bsrc + (size_t)i2 * CH + ch0;
      const ushort* p3 = bsrc + (size_t)i3 * CH + ch0;
      const ushort* p4 = bsrc + (size_t)i4 * CH + ch0;
      s16x8 ld0, ld1, ld2, ld3, ld4;
      asm volatile("global_load_dwordx4 %0, %1, off sc0" : "=&v"(ld0) : "v"(p0) : "memory");
      asm volatile("global_load_dwordx4 %0, %1, off sc0" : "=&v"(ld1) : "v"(p1) : "memory");
      asm volatile("global_load_dwordx4 %0, %1, off sc0" : "=&v"(ld2) : "v"(p2) : "memory");
      asm volatile("global_load_dwordx4 %0, %1, off sc0" : "=&v"(ld3) : "v"(p3) : "memory");
      asm volatile("global_load_dwordx4 %0, %1, off sc0" : "=&v"(ld4) : "v"(p4) : "memory");
      asm volatile("s_waitcnt vmcnt(0)" ::: "memory");
      __builtin_amdgcn_sched_barrier(0);
      // h = leaky(scale1*x + shift1), back to bf16 (same rounding chain as R1)
      auto xf = [&](s16x8 v) -> s16x8 {
        s16x8 r;
#pragma unroll
        for (int i = 0; i < 8; ++i) {
          float x = bf2f((ushort)v[i]);
          r[i] = (short)f2bf(leaky(sc8[i] * x + sh8[i]));
        }
        return r;
      };
      a0 = xf(ld0); a1 = xf(ld1); a2 = xf(ld2); a3 = xf(ld3); a4 = xf(ld4);
    }
    if (qh) { s16x8 z = {0,0,0,0,0,0,0,0}; a4 = z; }   // K-pad lanes (k>=144)

    f32x4 acc = {0.f, 0.f, 0.f, 0.f};
    acc = __builtin_amdgcn_mfma_f32_16x16x32_bf16(a0, bfrag[0], acc, 0, 0, 0);
    acc = __builtin_amdgcn_mfma_f32_16x16x32_bf16(a1, bfrag[1], acc, 0, 0, 0);
    acc = __builtin_amdgcn_mfma_f32_16x16x32_bf16(a2, bfrag[2], acc, 0, 0, 0);
    acc = __builtin_amdgcn_mfma_f32_16x16x32_bf16(a3, bfrag[3], acc, 0, 0, 0);
    acc = __builtin_amdgcn_mfma_f32_16x16x32_bf16(a4, bfrag[4], acc, 0, 0, 0);

    // D[m][o]: m = q*4+r (node within tile), o = lane&15 (channel)
#pragma unroll
    for (int r = 0; r < 4; ++r) {
      float v = acc[r] + bo;
      ushort hv = f2bf(v);
      outv[(size_t)(base + q * 4 + r) * CH + o] = hv;
      float vr = bf2f(hv);     // stats on the ROUNDED value (matches stored tensor)
      wsum += vr;
      wsq  += vr * vr;
    }
  }

  // per-channel reduce: lanes o, o+16, o+32, o+48 -> block -> global atomic
  wsum += __shfl_xor(wsum, 16);  wsum += __shfl_xor(wsum, 32);
  wsq  += __shfl_xor(wsq, 16);   wsq  += __shfl_xor(wsq, 32);
  if (lane < 16) { red[wid][lane] = wsum; red[wid][16 + lane] = wsq; }
  __syncthreads();
  if (threadIdx.x < 32) {
    float s = red[0][threadIdx.x] + red[1][threadIdx.x] + red[2][threadIdx.x] + red[3][threadIdx.x];
    atomicAdd(&accumOut[threadIdx.x], s);   // [0..15]=sum, [16..31]=sumsq
  }
}

// out = leaky(scale2*out2 + shift2 + data), fp32; BN2 derived per block
__global__ __launch_bounds__(256)
void k_final(const ushort* __restrict__ o2, const float* __restrict__ data,
             const float* __restrict__ statsIn, const float* __restrict__ gamma,
             const float* __restrict__ beta, float* __restrict__ out) {
  __shared__ float dsc[16], dsh[16];
  if (threadIdx.x < 16) {
    int c = threadIdx.x;
    float s = statsIn[c], sq = statsIn[16 + c];
    float mean = s * (1.0f / NN);
    float var  = sq * (1.0f / NN) - mean * mean;
    float scale = gamma[c] * rsqrtf(var + 1e-5f);
    dsc[c] = scale; dsh[c] = beta[c] - mean * scale;
  }
  __syncthreads();
  size_t t = (size_t)blockIdx.x * 256 + threadIdx.x;
  size_t i0 = t * 8;
  if (i0 >= (size_t)NN * CH) return;
  int coff = (int)(i0 & 15);
  float sc[8], sh[8];
#pragma unroll
  for (int p = 0; p < 8; ++p) { sc[p] = dsc[coff + p]; sh[p] = dsh[coff + p]; }
  uint4 a = *(const uint4*)(o2 + i0);
  float4 d0 = *(const float4*)(data + i0);
  float4 d1 = *(const float4*)(data + i0 + 4);
  uint ua[4] = {a.x, a.y, a.z, a.w};
  float dd[8] = {d0.x, d0.y, d0.z, d0.w, d1.x, d1.y, d1.z, d1.w};
  float y[8];
#pragma unroll
  for (int p = 0; p < 4; ++p) {
    float x0 = __uint_as_float(ua[p] << 16);
    float x1 = __uint_as_float(ua[p] & 0xffff0000u);
    y[2*p]   = leaky(sc[2*p]   * x0 + sh[2*p]   + dd[2*p]);
    y[2*p+1] = leaky(sc[2*p+1] * x1 + sh[2*p+1] + dd[2*p+1]);
  }
  float4 r0 = {y[0], y[1], y[2], y[3]};
  float4 r1 = {y[4], y[5], y[6], y[7]};
  *(float4*)(out + i0) = r0;
  *(float4*)(out + i0 + 4) = r1;
}

extern "C" void kernel_launch(void* const* d_in, const int* in_sizes, int n_in,
                              void* d_out, int out_size, void* d_ws, size_t ws_size,
                              hipStream_t stream) {
  const float* data   = (const float*)d_in[0];
  const int*   ind    = (const int*)d_in[1];
  const float* w1     = (const float*)d_in[2];
  const float* b1     = (const float*)d_in[3];
  const float* gamma1 = (const float*)d_in[4];
  const float* beta1  = (const float*)d_in[5];
  const float* w2     = (const float*)d_in[6];
  const float* gamma2 = (const float*)d_in[7];
  const float* beta2  = (const float*)d_in[8];
  float* out = (float*)d_out;

  // d_out (64MB fp32) doubles as scratch until k_final overwrites:
  //   [0,32MB) = out1 bf16 (conv1 raw output; conv2 applies BN1+leaky in gather)
  ushort* out1 = (ushort*)d_out;
  // ws: accum1[32] | accum2[32] | pad | out2 bf16 (32MB @ +4096)
  float*  accum1 = (float*)d_ws;
  float*  accum2 = accum1 + 32;
  ushort* out2   = (ushort*)((char*)d_ws + 4096);

  hipMemsetAsync(d_ws, 0, 256, stream);   // zero both stat accumulators

  // conv1: data (fp32, direct gather+convert) -> out1 raw + stats
  hipLaunchKernelGGL((k_conv<true>), dim3(NBLK), dim3(256), 0, stream,
                     (const void*)data, ind, w1, b1,
                     (const float*)nullptr, (const float*)nullptr, (const float*)nullptr,
                     out1, accum1);

  // conv2: gather out1, BN1+leaky in-register -> out2 raw + stats
  hipLaunchKernelGGL((k_conv<false>), dim3(NBLK), dim3(256), 0, stream,
                     (const void*)out1, ind, w2, (const float*)nullptr,
                     accum1, gamma1, beta1,
                     out2, accum2);

  // residual + BN2 + leaky -> d_out (scratch dead)
  hipLaunchKernelGGL(k_final, dim3((NN * CH / 8 + 255) / 256), dim3(256), 0, stream,
                     out2, data, accum2, gamma2, beta2, out);
}